// Round 2
// baseline (253.014 us; speedup 1.0000x reference)
//
#include <hip/hip_runtime.h>
#include <hip/hip_bf16.h>

// ---------------------------------------------------------------------------
// OuterProductMean (AlphaFold) fused MFMA implementation for gfx950.
//   B=1, N=128 (MSA depth), L=256, C_M=256, C_H=32, C_Z=128
// Pipeline:
//   k_wt      : [Wa|Wb] fp32 [256][32]x2 -> WT bf16 [64][256]   (h-major, c contiguous)
//   k_wot     : Wo fp32 [1024][128]      -> WoT bf16 [128][1024] (z-major, k contiguous)
//   k_pm      : pm_recip[i,j] = 1/(sum_n mask[n,i]*mask[n,j] + 1e-8)
//   k_ln_proj : LayerNorm + a/b projection (MFMA), writes aT/bT bf16 [8192][128]
//               (row = i*32+c / j*32+d, col = MSA index n  -> K-contiguous operand layout)
//   k_outer   : per 4x4 (i,j)-tile: outer 128x128 GEMM (K=128) fused with
//               [16 pairs,1024] @ Wo[1024,128] GEMM (K=1024), scale + bias epilogue.
// ---------------------------------------------------------------------------

typedef __attribute__((ext_vector_type(8))) short bf8_t;   // 8 x bf16 (4 VGPRs)
typedef __attribute__((ext_vector_type(4))) float f32x4;   // MFMA accumulator

__device__ __forceinline__ unsigned short f2bf(float f) {
    unsigned int u = __float_as_uint(f);
    u += 0x7fffu + ((u >> 16) & 1u);        // RNE (finite values only)
    return (unsigned short)(u >> 16);
}
__device__ __forceinline__ unsigned int pack2(float a, float b) {
    return (unsigned int)f2bf(a) | ((unsigned int)f2bf(b) << 16);
}

// ---------------------------------------------------------------------------
// WT[h][c] = (h<32 ? Wa[c][h] : Wb[c][h-32]), bf16. 16384 elems.
__global__ __launch_bounds__(256) void k_wt(const float* __restrict__ Wa,
                                            const float* __restrict__ Wb,
                                            unsigned short* __restrict__ WTb) {
    int u = blockIdx.x * 256 + threadIdx.x;          // u = h*256 + c
    int h = u >> 8, c = u & 255;
    float v = (h < 32) ? Wa[c * 32 + h] : Wb[c * 32 + (h - 32)];
    WTb[u] = f2bf(v);
}

// WoT[z][k] = Wo[k][z], bf16. 131072 elems.
__global__ __launch_bounds__(256) void k_wot(const float* __restrict__ Wo,
                                             unsigned short* __restrict__ WoT) {
    int u = blockIdx.x * 256 + threadIdx.x;          // u = k*128 + z
    int k = u >> 7, z = u & 127;
    WoT[(size_t)z * 1024 + k] = f2bf(Wo[u]);
}

// pm_recip[i*256+j] = 1/(sum_n mask[n,i]*mask[n,j] + 1e-8)
__global__ __launch_bounds__(256) void k_pm(const float* __restrict__ gmask,
                                            float* __restrict__ pmr) {
    int u = blockIdx.x * 256 + threadIdx.x;          // i = blockIdx.x, j = tid
    int i = u >> 8, j = u & 255;
    float s = 0.f;
    #pragma unroll 8
    for (int n = 0; n < 128; n++)
        s += gmask[n * 256 + i] * gmask[n * 256 + j];
    pmr[u] = 1.f / (s + 1e-8f);
}

// ---------------------------------------------------------------------------
// LayerNorm + projection. Block = 256 thr (4 waves), handles 16 MSA rows (n0..n0+15)
// at a fixed l. Phase1: LN per row -> bf16 x in swizzled LDS. Phase2: per-wave
// MFMA [16 rows x 256] @ WT -> 16x16 tile of (a|b). Phase3: repack -> aT/bT.
__global__ __launch_bounds__(256) void k_ln_proj(
    const float* __restrict__ gm, const float* __restrict__ gmask,
    const float* __restrict__ gamma, const float* __restrict__ beta,
    const unsigned short* __restrict__ WTb,
    const float* __restrict__ ba, const float* __restrict__ bb,
    unsigned short* __restrict__ aT, unsigned short* __restrict__ bT)
{
    __shared__ __align__(16) unsigned short xlb[16 * 256]; // [row][c] bf16, 8B-swizzled
    __shared__ float vl[16 * 64];                          // [n-row][h]
    const int tid = threadIdx.x, lane = tid & 63, w = tid >> 6;
    const int l = blockIdx.x & 255, n0 = (blockIdx.x >> 8) << 4;

    const float4 g4  = ((const float4*)gamma)[lane];
    const float4 be4 = ((const float4*)beta)[lane];

    // ---- phase 1: LN (wave per row, 4 rows per wave) ----
    #pragma unroll
    for (int j = 0; j < 4; j++) {
        int row = w * 4 + j;
        int n = n0 + row;
        float4 v = ((const float4*)(gm + ((size_t)n * 256 + l) * 256))[lane];
        float s = v.x + v.y + v.z + v.w;
        float q = v.x * v.x + v.y * v.y + v.z * v.z + v.w * v.w;
        #pragma unroll
        for (int off = 1; off < 64; off <<= 1) {
            s += __shfl_xor(s, off);
            q += __shfl_xor(q, off);
        }
        float mean = s * (1.f / 256.f);
        float var = fmaxf(q * (1.f / 256.f) - mean * mean, 0.f);
        float rstd = rsqrtf(var + 1e-5f);
        float x0 = (v.x - mean) * rstd * g4.x + be4.x;
        float x1 = (v.y - mean) * rstd * g4.y + be4.y;
        float x2 = (v.z - mean) * rstd * g4.z + be4.z;
        float x3 = (v.w - mean) * rstd * g4.w + be4.w;
        // lane owns c = 4*lane..4*lane+3 -> 8B sub-chunk index c8 = lane, XOR-swizzled
        int c8s = lane ^ ((row & 7) << 1);
        *(uint2*)((char*)xlb + row * 512 + (c8s << 3)) =
            make_uint2(pack2(x0, x1), pack2(x2, x3));
    }
    __syncthreads();

    // ---- phase 2: projection via MFMA (wave w -> h-cols w*16..w*16+15) ----
    const int kg = lane >> 4, r16 = lane & 15;
    const int h = w * 16 + r16;
    f32x4 acc = {0.f, 0.f, 0.f, 0.f};
    #pragma unroll
    for (int ks = 0; ks < 8; ks++) {
        int c8 = ks * 8 + kg * 2;                       // even -> swizzle keeps 16B pair
        bf8_t af = *(const bf8_t*)((char*)xlb + r16 * 512 +
                                   ((c8 ^ ((r16 & 7) << 1)) << 3));
        bf8_t wf = *(const bf8_t*)(WTb + (size_t)h * 256 + ks * 32 + kg * 8);
        acc = __builtin_amdgcn_mfma_f32_16x16x32_bf16(af, wf, acc, 0, 0, 0);
    }
    float bias = (h < 32) ? ba[h] : bb[h - 32];
    #pragma unroll
    for (int r = 0; r < 4; r++) {
        int nrow = kg * 4 + r;                          // C/D row = MSA row index
        float mk = gmask[(size_t)(n0 + nrow) * 256 + l];
        vl[nrow * 64 + h] = (acc[r] + bias) * mk;
    }
    __syncthreads();

    // ---- phase 3: repack 16 n-values per output row, 32B stores ----
    if (tid < 64) {
        int hh = tid & 31;
        unsigned short* dst = (tid < 32) ? aT : bT;
        unsigned int pk[8];
        #pragma unroll
        for (int jj = 0; jj < 8; jj++)
            pk[jj] = pack2(vl[(2 * jj) * 64 + tid], vl[(2 * jj + 1) * 64 + tid]);
        uint4* dp = (uint4*)(dst + ((size_t)l * 32 + hh) * 128 + n0);
        dp[0] = make_uint4(pk[0], pk[1], pk[2], pk[3]);
        dp[1] = make_uint4(pk[4], pk[5], pk[6], pk[7]);
    }
}

// ---------------------------------------------------------------------------
// Fused outer-product + Wo projection.
// Grid 4096 = 64 tj (fast) x 64 ti. Block 256 thr = 4 waves (2x2 quadrants).
__global__ __launch_bounds__(256) void k_outer(
    const unsigned short* __restrict__ aT, const unsigned short* __restrict__ bT,
    const unsigned short* __restrict__ WoT, const float* __restrict__ pmr,
    const float* __restrict__ bo, float* __restrict__ out)
{
    __shared__ __align__(16) char smem[65536];
    const int tid = threadIdx.x, lane = tid & 63, w = tid >> 6;
    const int wr = w >> 1, wc = w & 1;
    const int tj = blockIdx.x & 63, ti = blockIdx.x >> 6;
    const int kg = lane >> 4, r16 = lane & 15;

    // ---- stage A/B tiles: 128 rows x 128 k, bf16, 16B-chunk XOR swizzle ----
    {
        const uint4* gA = (const uint4*)(aT + (size_t)ti * 16384);
        const uint4* gB = (const uint4*)(bT + (size_t)tj * 16384);
        #pragma unroll
        for (int k = 0; k < 8; k++) {
            int g = k * 256 + tid;                      // 16B chunk id, coalesced
            int mrow = g >> 4, ch = g & 15;
            int dsto = mrow * 256 + ((ch ^ (mrow & 7)) << 4);
            *(uint4*)(smem + dsto) = gA[g];
            *(uint4*)(smem + 32768 + dsto) = gB[g];
        }
    }
    __syncthreads();

    // ---- stage 1: 128x128 outer tile, K=128 (4 k-steps of 32) ----
    f32x4 acc[4][4];
    #pragma unroll
    for (int mt = 0; mt < 4; mt++)
        #pragma unroll
        for (int nt = 0; nt < 4; nt++)
            acc[mt][nt] = (f32x4){0.f, 0.f, 0.f, 0.f};

    #pragma unroll
    for (int ks = 0; ks < 4; ks++) {
        bf8_t af[4], bfr[4];
        int ch = ks * 4 + kg;
        #pragma unroll
        for (int mt = 0; mt < 4; mt++) {
            int mm = wr * 64 + mt * 16 + r16;
            af[mt] = *(const bf8_t*)(smem + mm * 256 + ((ch ^ (mm & 7)) << 4));
            int nn = wc * 64 + mt * 16 + r16;
            bfr[mt] = *(const bf8_t*)(smem + 32768 + nn * 256 + ((ch ^ (nn & 7)) << 4));
        }
        #pragma unroll
        for (int mt = 0; mt < 4; mt++)
            #pragma unroll
            for (int nt = 0; nt < 4; nt++)
                acc[mt][nt] = __builtin_amdgcn_mfma_f32_16x16x32_bf16(
                    af[mt], bfr[nt], acc[mt][nt], 0, 0, 0);
    }
    __syncthreads();   // all waves done reading sA/sB -> safe to alias with O2

    // ---- transpose accs -> O2[p][k2] fp32 in LDS (bank-swizzled) ----
    float* O2 = (float*)smem;
    #pragma unroll
    for (int mt = 0; mt < 4; mt++) {
        #pragma unroll
        for (int nt = 0; nt < 4; nt++) {
            #pragma unroll
            for (int r = 0; r < 4; r++) {
                int mm = wr * 64 + mt * 16 + kg * 4 + r;   // C/D: row=(lane>>4)*4+reg
                int nn = wc * 64 + nt * 16 + r16;          //      col=lane&15
                int p  = ((mm >> 5) << 2) | (nn >> 5);     // pair = i_loc*4 + j_loc
                int k2 = ((mm & 31) << 5) | (nn & 31);     // k2 = c*32 + d
                int ch2 = k2 >> 2;
                int ch2s = ch2 ^ (p & 7) ^ (((ch2 >> 5) & 1) << 2);
                O2[p * 1024 + (ch2s << 2) + (k2 & 3)] = acc[mt][nt][r];
            }
        }
    }
    __syncthreads();

    // ---- stage 2: Z[16 pairs, 128] = O2[16,1024] @ Wo[1024,128] ----
    f32x4 acc2[2];
    acc2[0] = (f32x4){0.f, 0.f, 0.f, 0.f};
    acc2[1] = (f32x4){0.f, 0.f, 0.f, 0.f};
    const float4* O2v = (const float4*)smem;
    const int p2 = r16;                                    // A-operand row = pair
    #pragma unroll 4
    for (int s = 0; s < 32; s++) {
        int ch2a = s * 8 + kg * 2;                         // even
        int sw = (p2 & 7) ^ (((ch2a >> 5) & 1) << 2);
        float4 fa = O2v[p2 * 256 + (ch2a ^ sw)];
        float4 fb = O2v[p2 * 256 + ((ch2a + 1) ^ sw)];
        union { bf8_t v; unsigned int u[4]; } ua;
        ua.u[0] = pack2(fa.x, fa.y);
        ua.u[1] = pack2(fa.z, fa.w);
        ua.u[2] = pack2(fb.x, fb.y);
        ua.u[3] = pack2(fb.z, fb.w);
        #pragma unroll
        for (int nt2 = 0; nt2 < 2; nt2++) {
            int z = w * 32 + nt2 * 16 + r16;
            bf8_t wf = *(const bf8_t*)(WoT + (size_t)z * 1024 + s * 32 + kg * 8);
            acc2[nt2] = __builtin_amdgcn_mfma_f32_16x16x32_bf16(ua.v, wf, acc2[nt2], 0, 0, 0);
        }
    }

    // ---- epilogue: scale by 1/(pair_mask+eps), add bias, store ----
    const int i0 = ti * 4, j0 = tj * 4;
    #pragma unroll
    for (int r = 0; r < 4; r++) {
        int p = kg * 4 + r;
        int i = i0 + (p >> 2), j = j0 + (p & 3);
        float recip = pmr[i * 256 + j];
        #pragma unroll
        for (int nt2 = 0; nt2 < 2; nt2++) {
            int z = w * 32 + nt2 * 16 + r16;
            out[((size_t)(i * 256 + j)) * 128 + z] = acc2[nt2][r] * recip + bo[z];
        }
    }
}

// ---------------------------------------------------------------------------
extern "C" void kernel_launch(void* const* d_in, const int* in_sizes, int n_in,
                              void* d_out, int out_size, void* d_ws, size_t ws_size,
                              hipStream_t stream)
{
    const float* m    = (const float*)d_in[0];
    const float* mask = (const float*)d_in[1];
    const float* gam  = (const float*)d_in[2];
    const float* bet  = (const float*)d_in[3];
    const float* Wa   = (const float*)d_in[4];
    const float* ba   = (const float*)d_in[5];
    const float* Wb   = (const float*)d_in[6];
    const float* bb   = (const float*)d_in[7];
    const float* Wo   = (const float*)d_in[8];
    const float* bo   = (const float*)d_in[9];
    float* out = (float*)d_out;

    unsigned short* aT  = (unsigned short*)d_ws;           // 8192*128 bf16 = 2 MB
    unsigned short* bT  = aT + 8192 * 128;                 // 2 MB
    unsigned short* WoT = bT + 8192 * 128;                 // 128*1024 bf16 = 256 KB
    unsigned short* WTb = WoT + 128 * 1024;                // 64*256 bf16 = 32 KB
    float* pmr = (float*)(WTb + 64 * 256);                 // 256*256 fp32 = 256 KB

    k_wt     <<<  64, 256, 0, stream>>>(Wa, Wb, WTb);
    k_wot    <<< 512, 256, 0, stream>>>(Wo, WoT);
    k_pm     <<< 256, 256, 0, stream>>>(mask, pmr);
    k_ln_proj<<<2048, 256, 0, stream>>>(m, mask, gam, bet, WTb, ba, bb, aT, bT);
    k_outer  <<<4096, 256, 0, stream>>>(aT, bT, WoT, pmr, bo, out);
}

// Round 3
// 247.828 us; speedup vs baseline: 1.0209x; 1.0209x over previous
//
#include <hip/hip_runtime.h>
#include <hip/hip_bf16.h>

// ---------------------------------------------------------------------------
// OuterProductMean (AlphaFold) fused MFMA implementation for gfx950.
//   B=1, N=128 (MSA depth), L=256, C_M=256, C_H=32, C_Z=128
// Pipeline (3 launches):
//   k_prep    : [Wa|Wb] fp32 -> WT bf16 [64][256] (h-major, c contiguous)
//   k_ln_proj : main blocks: LayerNorm + a/b projection (MFMA) -> aT/bT bf16
//               [8192][128] (row = l*32+h, col = MSA index n -> K-contiguous).
//               tail blocks: WoT bf16 [128][1024] with k' = d*32+c ordering,
//               and pm_recip[i,j] = 1/(sum_n mask[n,i]*mask[n,j] + 1e-8).
//   k_outer   : per 4x4 (i,j)-tile: outer 128x128 GEMM (K=128), transpose to
//               bf16 A-fragment layout in LDS, then [16,1024]@Wo[1024,128]
//               GEMM, scale + bias epilogue. All-MFMA, no fp32->bf16 in the
//               stage-2 K-loop (conversion folded into the transpose).
// ---------------------------------------------------------------------------

typedef __attribute__((ext_vector_type(8))) short bf8_t;   // 8 x bf16 (4 VGPRs)
typedef __attribute__((ext_vector_type(4))) float f32x4;   // MFMA accumulator

__device__ __forceinline__ unsigned short f2bf(float f) {
    unsigned int u = __float_as_uint(f);
    u += 0x7fffu + ((u >> 16) & 1u);        // RNE (finite values only)
    return (unsigned short)(u >> 16);
}
__device__ __forceinline__ unsigned int pack2(float a, float b) {
    return (unsigned int)f2bf(a) | ((unsigned int)f2bf(b) << 16);
}

// ---------------------------------------------------------------------------
// WT[h][c] = (h<32 ? Wa[c][h] : Wb[c][h-32]), bf16. 16384 elems, 64 blocks.
__global__ __launch_bounds__(256) void k_prep(const float* __restrict__ Wa,
                                              const float* __restrict__ Wb,
                                              unsigned short* __restrict__ WTb) {
    int u = blockIdx.x * 256 + threadIdx.x;          // u = h*256 + c
    int h = u >> 8, c = u & 255;
    float v = (h < 32) ? Wa[c * 32 + h] : Wb[c * 32 + (h - 32)];
    WTb[u] = f2bf(v);
}

// ---------------------------------------------------------------------------
// Blocks [0,2048): LayerNorm + projection. Block = 256 thr (4 waves), 16 MSA
// rows (n0..n0+15) at fixed l. Blocks [2048,2560): WoT transpose (k'=d*32+c).
// Blocks [2560,2816): pair-mask reciprocal.
__global__ __launch_bounds__(256) void k_ln_proj(
    const float* __restrict__ gm, const float* __restrict__ gmask,
    const float* __restrict__ gamma, const float* __restrict__ beta,
    const unsigned short* __restrict__ WTb,
    const float* __restrict__ ba, const float* __restrict__ bb,
    const float* __restrict__ Wo,
    unsigned short* __restrict__ aT, unsigned short* __restrict__ bT,
    unsigned short* __restrict__ WoT, float* __restrict__ pmr)
{
    const int tid = threadIdx.x;
    const int tail = (int)blockIdx.x - 2048;
    if (tail >= 0) {
        if (tail < 512) {
            // WoT[z][d*32+c] = Wo[(c*32+d)*128 + z], coalesced writes
            int u = tail * 256 + tid;                // u = z*1024 + k'
            int z = u >> 10, kp = u & 1023;
            int d = kp >> 5, c = kp & 31;
            WoT[u] = f2bf(Wo[(size_t)(c * 32 + d) * 128 + z]);
        } else {
            int u = (tail - 512) * 256 + tid;        // u = i*256 + j
            int i = u >> 8, j = u & 255;
            float s = 0.f;
            #pragma unroll 8
            for (int n = 0; n < 128; n++)
                s += gmask[n * 256 + i] * gmask[n * 256 + j];
            pmr[u] = 1.f / (s + 1e-8f);
        }
        return;
    }

    __shared__ __align__(16) unsigned short xlb[16 * 256]; // [row][c] bf16, swizzled
    __shared__ float vl[16 * 64];                          // [n-row][h]
    const int lane = tid & 63, w = tid >> 6;
    const int l = blockIdx.x & 255, n0 = ((int)blockIdx.x >> 8) << 4;

    const float4 g4  = ((const float4*)gamma)[lane];
    const float4 be4 = ((const float4*)beta)[lane];

    // ---- phase 1: LN (wave per row, 4 rows per wave) ----
    #pragma unroll
    for (int j = 0; j < 4; j++) {
        int row = w * 4 + j;
        int n = n0 + row;
        float4 v = ((const float4*)(gm + ((size_t)n * 256 + l) * 256))[lane];
        float s = v.x + v.y + v.z + v.w;
        float q = v.x * v.x + v.y * v.y + v.z * v.z + v.w * v.w;
        #pragma unroll
        for (int off = 1; off < 64; off <<= 1) {
            s += __shfl_xor(s, off);
            q += __shfl_xor(q, off);
        }
        float mean = s * (1.f / 256.f);
        float var = fmaxf(q * (1.f / 256.f) - mean * mean, 0.f);
        float rstd = rsqrtf(var + 1e-5f);
        float x0 = (v.x - mean) * rstd * g4.x + be4.x;
        float x1 = (v.y - mean) * rstd * g4.y + be4.y;
        float x2 = (v.z - mean) * rstd * g4.z + be4.z;
        float x3 = (v.w - mean) * rstd * g4.w + be4.w;
        int c8s = lane ^ ((row & 7) << 1);               // 8B-chunk XOR swizzle
        *(uint2*)((char*)xlb + row * 512 + (c8s << 3)) =
            make_uint2(pack2(x0, x1), pack2(x2, x3));
    }
    __syncthreads();

    // ---- phase 2: projection via MFMA (wave w -> h-cols w*16..w*16+15) ----
    const int kg = lane >> 4, r16 = lane & 15;
    const int h = w * 16 + r16;
    f32x4 acc = {0.f, 0.f, 0.f, 0.f};
    #pragma unroll
    for (int ks = 0; ks < 8; ks++) {
        int c8 = ks * 8 + kg * 2;                        // even -> 16B pair intact
        bf8_t af = *(const bf8_t*)((char*)xlb + r16 * 512 +
                                   ((c8 ^ ((r16 & 7) << 1)) << 3));
        bf8_t wf = *(const bf8_t*)(WTb + (size_t)h * 256 + ks * 32 + kg * 8);
        acc = __builtin_amdgcn_mfma_f32_16x16x32_bf16(af, wf, acc, 0, 0, 0);
    }
    float bias = (h < 32) ? ba[h] : bb[h - 32];
    #pragma unroll
    for (int r = 0; r < 4; r++) {
        int nrow = kg * 4 + r;                           // C/D row = MSA row index
        float mk = gmask[(size_t)(n0 + nrow) * 256 + l];
        vl[nrow * 64 + h] = (acc[r] + bias) * mk;
    }
    __syncthreads();

    // ---- phase 3: repack, 8 n-values per thread, 16B stores ----
    if (tid < 128) {
        int row = tid >> 1, half = tid & 1;              // row = h index 0..63
        int hh = row & 31;
        unsigned short* dst = (row < 32) ? aT : bT;
        unsigned int pk[4];
        #pragma unroll
        for (int jj = 0; jj < 4; jj++)
            pk[jj] = pack2(vl[(half * 8 + 2 * jj) * 64 + row],
                           vl[(half * 8 + 2 * jj + 1) * 64 + row]);
        *(uint4*)(dst + ((size_t)l * 32 + hh) * 128 + n0 + half * 8) =
            make_uint4(pk[0], pk[1], pk[2], pk[3]);
    }
}

// ---------------------------------------------------------------------------
// Fused outer-product + Wo projection.
// Grid 4096 = 64 tj (fast) x 64 ti. Block 256 thr = 4 waves (2x2 quadrants).
__global__ __launch_bounds__(256) void k_outer(
    const unsigned short* __restrict__ aT, const unsigned short* __restrict__ bT,
    const unsigned short* __restrict__ WoT, const float* __restrict__ pmr,
    const float* __restrict__ bo, float* __restrict__ out)
{
    __shared__ __align__(16) char smem[65536];
    const int tid = threadIdx.x, lane = tid & 63, w = tid >> 6;
    const int wr = w >> 1, wc = w & 1;
    const int tj = blockIdx.x & 63, ti = blockIdx.x >> 6;
    const int kg = lane >> 4, r16 = lane & 15;

    // ---- stage A/B tiles: 128 rows x 128 k, bf16, 16B-chunk XOR swizzle ----
    {
        const uint4* gA = (const uint4*)(aT + (size_t)ti * 16384);
        const uint4* gB = (const uint4*)(bT + (size_t)tj * 16384);
        #pragma unroll
        for (int k = 0; k < 8; k++) {
            int g = k * 256 + tid;                      // 16B chunk id, coalesced
            int mrow = g >> 4, ch = g & 15;
            int dsto = mrow * 256 + ((ch ^ (mrow & 7)) << 4);
            *(uint4*)(smem + dsto) = gA[g];
            *(uint4*)(smem + 32768 + dsto) = gB[g];
        }
    }
    __syncthreads();

    // ---- stage 1: 128x128 outer tile, K=128 (4 k-steps of 32) ----
    f32x4 acc[4][4];
    #pragma unroll
    for (int mt = 0; mt < 4; mt++)
        #pragma unroll
        for (int nt = 0; nt < 4; nt++)
            acc[mt][nt] = (f32x4){0.f, 0.f, 0.f, 0.f};

    #pragma unroll
    for (int ks = 0; ks < 4; ks++) {
        bf8_t af[4], bfr[4];
        int ch = ks * 4 + kg;
        #pragma unroll
        for (int mt = 0; mt < 4; mt++) {
            int mm = wr * 64 + mt * 16 + r16;
            af[mt] = *(const bf8_t*)(smem + mm * 256 + ((ch ^ (mm & 7)) << 4));
            int nn = wc * 64 + mt * 16 + r16;
            bfr[mt] = *(const bf8_t*)(smem + 32768 + nn * 256 + ((ch ^ (nn & 7)) << 4));
        }
        #pragma unroll
        for (int mt = 0; mt < 4; mt++)
            #pragma unroll
            for (int nt = 0; nt < 4; nt++)
                acc[mt][nt] = __builtin_amdgcn_mfma_f32_16x16x32_bf16(
                    af[mt], bfr[nt], acc[mt][nt], 0, 0, 0);
    }
    __syncthreads();   // all waves done reading sA/sB -> safe to alias with O2b

    // ---- transpose accs -> O2b[p][k2] bf16 in LDS, A-fragment order ----
    // k2 = (nn&31)*32 + (mm&31)  (d-major) -> 4 acc regs are k2-consecutive.
    // chunk swizzle: pc = (k2>>3) ^ (p&7); WoT built with matching k' order.
    unsigned short* O2b = (unsigned short*)smem;        // 16 x 1024 bf16 = 32 KB
    #pragma unroll
    for (int mt = 0; mt < 4; mt++) {
        int mmb = wr * 64 + mt * 16 + kg * 4;           // + r (r stays in-chunk)
        #pragma unroll
        for (int nt = 0; nt < 4; nt++) {
            int nn = wc * 64 + nt * 16 + r16;
            int p  = ((mmb >> 5) << 2) | (nn >> 5);     // pair = i_loc*4 + j_loc
            int k2 = ((nn & 31) << 5) | (mmb & 31);
            int pc = (k2 >> 3) ^ (p & 7);
            *(uint2*)(O2b + p * 1024 + pc * 8 + (k2 & 7)) =
                make_uint2(pack2(acc[mt][nt][0], acc[mt][nt][1]),
                           pack2(acc[mt][nt][2], acc[mt][nt][3]));
        }
    }
    __syncthreads();

    // ---- stage 2: Z[16 pairs, 128] = O2[16,1024] @ Wo[1024,128] ----
    f32x4 acc2[2];
    acc2[0] = (f32x4){0.f, 0.f, 0.f, 0.f};
    acc2[1] = (f32x4){0.f, 0.f, 0.f, 0.f};
    const int p2 = r16;                                  // A-operand row = pair
    const unsigned short* O2r = O2b + p2 * 1024;
    const int psw = p2 & 7;
    const unsigned short* w0 = WoT + (size_t)(w * 32 + r16) * 1024 + kg * 8;
    const unsigned short* w1 = w0 + 16 * 1024;
    #pragma unroll 8
    for (int s = 0; s < 32; s++) {
        int pc = (s * 4 + kg) ^ psw;
        bf8_t av  = *(const bf8_t*)(O2r + pc * 8);
        bf8_t wfa = *(const bf8_t*)(w0 + s * 32);
        bf8_t wfb = *(const bf8_t*)(w1 + s * 32);
        acc2[0] = __builtin_amdgcn_mfma_f32_16x16x32_bf16(av, wfa, acc2[0], 0, 0, 0);
        acc2[1] = __builtin_amdgcn_mfma_f32_16x16x32_bf16(av, wfb, acc2[1], 0, 0, 0);
    }

    // ---- epilogue: scale by 1/(pair_mask+eps), add bias, store ----
    const int i0 = ti * 4, j0 = tj * 4;
    #pragma unroll
    for (int r = 0; r < 4; r++) {
        int p = kg * 4 + r;
        int i = i0 + (p >> 2), j = j0 + (p & 3);
        float recip = pmr[i * 256 + j];
        #pragma unroll
        for (int nt2 = 0; nt2 < 2; nt2++) {
            int z = w * 32 + nt2 * 16 + r16;
            out[((size_t)(i * 256 + j)) * 128 + z] = acc2[nt2][r] * recip + bo[z];
        }
    }
}

// ---------------------------------------------------------------------------
extern "C" void kernel_launch(void* const* d_in, const int* in_sizes, int n_in,
                              void* d_out, int out_size, void* d_ws, size_t ws_size,
                              hipStream_t stream)
{
    const float* m    = (const float*)d_in[0];
    const float* mask = (const float*)d_in[1];
    const float* gam  = (const float*)d_in[2];
    const float* bet  = (const float*)d_in[3];
    const float* Wa   = (const float*)d_in[4];
    const float* ba   = (const float*)d_in[5];
    const float* Wb   = (const float*)d_in[6];
    const float* bb   = (const float*)d_in[7];
    const float* Wo   = (const float*)d_in[8];
    const float* bo   = (const float*)d_in[9];
    float* out = (float*)d_out;

    unsigned short* aT  = (unsigned short*)d_ws;           // 8192*128 bf16 = 2 MB
    unsigned short* bT  = aT + 8192 * 128;                 // 2 MB
    unsigned short* WoT = bT + 8192 * 128;                 // 128*1024 bf16 = 256 KB
    unsigned short* WTb = WoT + 128 * 1024;                // 64*256 bf16 = 32 KB
    float* pmr = (float*)(WTb + 64 * 256);                 // 256*256 fp32 = 256 KB

    k_prep   <<<  64, 256, 0, stream>>>(Wa, Wb, WTb);
    k_ln_proj<<<2816, 256, 0, stream>>>(m, mask, gam, bet, WTb, ba, bb, Wo,
                                        aT, bT, WoT, pmr);
    k_outer  <<<4096, 256, 0, stream>>>(aT, bT, WoT, pmr, bo, out);
}

// Round 4
// 228.860 us; speedup vs baseline: 1.1055x; 1.0829x over previous
//
#include <hip/hip_runtime.h>
#include <hip/hip_bf16.h>

// ---------------------------------------------------------------------------
// OuterProductMean (AlphaFold) fused MFMA implementation for gfx950.
//   B=1, N=128 (MSA depth), L=256, C_M=256, C_H=32, C_Z=128
// Pipeline (3 launches):
//   k_prep    : [Wa|Wb] fp32 -> WT bf16 [64][256] (h-major, c contiguous)
//   k_ln_proj : main blocks: LayerNorm + a/b projection (MFMA) -> aT/bT bf16
//               [8192][128] (row = l*32+h, col = MSA index n -> K-contiguous).
//               tail: W2 = Wo in bf16 *fragment-sequential* layout
//               (zg,s,r16,kg,e) so stage-2 wave loads are contiguous 1KB;
//               pm_recip[i,j] = 1/(sum_n mask[n,i]*mask[n,j] + 1e-8).
//   k_outer   : 32KB LDS only (5 blocks/CU): K-split (2x K=64) staging for the
//               128x128 outer GEMM, transpose to bf16 A-fragment layout in the
//               same LDS, then [16,1024]@Wo[1024,128] GEMM, scale+bias epilogue.
// ---------------------------------------------------------------------------

typedef __attribute__((ext_vector_type(8))) short bf8_t;   // 8 x bf16 (4 VGPRs)
typedef __attribute__((ext_vector_type(4))) float f32x4;   // MFMA accumulator

__device__ __forceinline__ unsigned short f2bf(float f) {
    unsigned int u = __float_as_uint(f);
    u += 0x7fffu + ((u >> 16) & 1u);        // RNE (finite values only)
    return (unsigned short)(u >> 16);
}
__device__ __forceinline__ unsigned int pack2(float a, float b) {
    return (unsigned int)f2bf(a) | ((unsigned int)f2bf(b) << 16);
}

// ---------------------------------------------------------------------------
// WT[h][c] = (h<32 ? Wa[c][h] : Wb[c][h-32]), bf16. 16384 elems, 64 blocks.
__global__ __launch_bounds__(256) void k_prep(const float* __restrict__ Wa,
                                              const float* __restrict__ Wb,
                                              unsigned short* __restrict__ WTb) {
    int u = blockIdx.x * 256 + threadIdx.x;          // u = h*256 + c
    int h = u >> 8, c = u & 255;
    float v = (h < 32) ? Wa[c * 32 + h] : Wb[c * 32 + (h - 32)];
    WTb[u] = f2bf(v);
}

// ---------------------------------------------------------------------------
// Blocks [0,2048): LayerNorm + projection. Blocks [2048,2560): W2 build.
// Blocks [2560,2816): pair-mask reciprocal.
__global__ __launch_bounds__(256) void k_ln_proj(
    const float* __restrict__ gm, const float* __restrict__ gmask,
    const float* __restrict__ gamma, const float* __restrict__ beta,
    const unsigned short* __restrict__ WTb,
    const float* __restrict__ ba, const float* __restrict__ bb,
    const float* __restrict__ Wo,
    unsigned short* __restrict__ aT, unsigned short* __restrict__ bT,
    unsigned short* __restrict__ W2, float* __restrict__ pmr)
{
    const int tid = threadIdx.x;
    const int tail = (int)blockIdx.x - 2048;
    if (tail >= 0) {
        if (tail < 512) {
            // W2 fragment-sequential: (zg=z>>4, s=k'>>5, r16=z&15, kg=(k'>>3)&3, e=k'&7)
            // with k' = d*32+c, Wo element index u = (c*32+d)*128 + z.
            int u = tail * 256 + tid;                // u = k*128 + z (coalesced read)
            int k = u >> 7, z = u & 127;
            int c = k >> 5, d = k & 31;
            int kp = d * 32 + c;
            int dst = (((z >> 4) * 32 + (kp >> 5)) * 16 + (z & 15)) * 32
                      + ((kp >> 3) & 3) * 8 + (kp & 7);
            W2[dst] = f2bf(Wo[u]);
        } else {
            int u = (tail - 512) * 256 + tid;        // u = i*256 + j
            int i = u >> 8, j = u & 255;
            float s = 0.f;
            #pragma unroll 8
            for (int n = 0; n < 128; n++)
                s += gmask[n * 256 + i] * gmask[n * 256 + j];
            pmr[u] = 1.f / (s + 1e-8f);
        }
        return;
    }

    __shared__ __align__(16) unsigned short xlb[16 * 256]; // [row][c] bf16, swizzled
    __shared__ float vl[16 * 64];                          // [n-row][h]
    const int lane = tid & 63, w = tid >> 6;
    const int l = blockIdx.x & 255, n0 = ((int)blockIdx.x >> 8) << 4;

    const float4 g4  = ((const float4*)gamma)[lane];
    const float4 be4 = ((const float4*)beta)[lane];

    // ---- phase 1: LN (wave per row, 4 rows per wave) ----
    #pragma unroll
    for (int j = 0; j < 4; j++) {
        int row = w * 4 + j;
        int n = n0 + row;
        float4 v = ((const float4*)(gm + ((size_t)n * 256 + l) * 256))[lane];
        float s = v.x + v.y + v.z + v.w;
        float q = v.x * v.x + v.y * v.y + v.z * v.z + v.w * v.w;
        #pragma unroll
        for (int off = 1; off < 64; off <<= 1) {
            s += __shfl_xor(s, off);
            q += __shfl_xor(q, off);
        }
        float mean = s * (1.f / 256.f);
        float var = fmaxf(q * (1.f / 256.f) - mean * mean, 0.f);
        float rstd = rsqrtf(var + 1e-5f);
        float x0 = (v.x - mean) * rstd * g4.x + be4.x;
        float x1 = (v.y - mean) * rstd * g4.y + be4.y;
        float x2 = (v.z - mean) * rstd * g4.z + be4.z;
        float x3 = (v.w - mean) * rstd * g4.w + be4.w;
        int c8s = lane ^ ((row & 7) << 1);               // 8B-chunk XOR swizzle
        *(uint2*)((char*)xlb + row * 512 + (c8s << 3)) =
            make_uint2(pack2(x0, x1), pack2(x2, x3));
    }
    __syncthreads();

    // ---- phase 2: projection via MFMA (wave w -> h-cols w*16..w*16+15) ----
    const int kg = lane >> 4, r16 = lane & 15;
    const int h = w * 16 + r16;
    f32x4 acc = {0.f, 0.f, 0.f, 0.f};
    #pragma unroll
    for (int ks = 0; ks < 8; ks++) {
        int c8 = ks * 8 + kg * 2;                        // even -> 16B pair intact
        bf8_t af = *(const bf8_t*)((char*)xlb + r16 * 512 +
                                   ((c8 ^ ((r16 & 7) << 1)) << 3));
        bf8_t wf = *(const bf8_t*)(WTb + (size_t)h * 256 + ks * 32 + kg * 8);
        acc = __builtin_amdgcn_mfma_f32_16x16x32_bf16(af, wf, acc, 0, 0, 0);
    }
    float bias = (h < 32) ? ba[h] : bb[h - 32];
    #pragma unroll
    for (int r = 0; r < 4; r++) {
        int nrow = kg * 4 + r;                           // C/D row = MSA row index
        float mk = gmask[(size_t)(n0 + nrow) * 256 + l];
        vl[nrow * 64 + h] = (acc[r] + bias) * mk;
    }
    __syncthreads();

    // ---- phase 3: repack, 8 n-values per thread, 16B stores ----
    if (tid < 128) {
        int row = tid >> 1, half = tid & 1;              // row = h index 0..63
        int hh = row & 31;
        unsigned short* dst = (row < 32) ? aT : bT;
        unsigned int pk[4];
        #pragma unroll
        for (int jj = 0; jj < 4; jj++)
            pk[jj] = pack2(vl[(half * 8 + 2 * jj) * 64 + row],
                           vl[(half * 8 + 2 * jj + 1) * 64 + row]);
        *(uint4*)(dst + ((size_t)l * 32 + hh) * 128 + n0 + half * 8) =
            make_uint4(pk[0], pk[1], pk[2], pk[3]);
    }
}

// ---------------------------------------------------------------------------
// Fused outer-product + Wo projection. 32KB LDS -> 5 blocks/CU.
// Grid 4096 = 64 tj (fast) x 64 ti. Block 256 thr = 4 waves (2x2 quadrants).
__global__ __launch_bounds__(256, 5) void k_outer(
    const unsigned short* __restrict__ aT, const unsigned short* __restrict__ bT,
    const unsigned short* __restrict__ W2, const float* __restrict__ pmr,
    const float* __restrict__ bo, float* __restrict__ out)
{
    __shared__ __align__(16) char smem[32768];
    const int tid = threadIdx.x, lane = tid & 63, w = tid >> 6;
    const int wr = w >> 1, wc = w & 1;
    const int tj = blockIdx.x & 63, ti = blockIdx.x >> 6;
    const int kg = lane >> 4, r16 = lane & 15;

    f32x4 acc[4][4];
    #pragma unroll
    for (int mt = 0; mt < 4; mt++)
        #pragma unroll
        for (int nt = 0; nt < 4; nt++)
            acc[mt][nt] = (f32x4){0.f, 0.f, 0.f, 0.f};

    const uint4* gA = (const uint4*)(aT + (size_t)ti * 16384);
    const uint4* gB = (const uint4*)(bT + (size_t)tj * 16384);

    // ---- stage 1: 128x128 outer tile in two K=64 rounds (16KB A + 16KB B) ----
    #pragma unroll
    for (int half = 0; half < 2; half++) {
        #pragma unroll
        for (int k = 0; k < 4; k++) {
            int g = k * 256 + tid;                       // 0..1023
            int row = g >> 3, ch = g & 7;                // row 0..127, chunk-in-half
            int dsto = row * 128 + ((ch ^ (row & 7)) << 4);
            *(uint4*)(smem + dsto)         = gA[row * 16 + half * 8 + ch];
            *(uint4*)(smem + 16384 + dsto) = gB[row * 16 + half * 8 + ch];
        }
        __syncthreads();
        #pragma unroll
        for (int ks2 = 0; ks2 < 2; ks2++) {
            bf8_t af[4], bfr[4];
            int ch = ks2 * 4 + kg;                       // chunk within half
            #pragma unroll
            for (int mt = 0; mt < 4; mt++) {
                int mm = wr * 64 + mt * 16 + r16;
                af[mt] = *(const bf8_t*)(smem + mm * 128 + ((ch ^ (mm & 7)) << 4));
                int nn = wc * 64 + mt * 16 + r16;
                bfr[mt] = *(const bf8_t*)(smem + 16384 + nn * 128 + ((ch ^ (nn & 7)) << 4));
            }
            #pragma unroll
            for (int mt = 0; mt < 4; mt++)
                #pragma unroll
                for (int nt = 0; nt < 4; nt++)
                    acc[mt][nt] = __builtin_amdgcn_mfma_f32_16x16x32_bf16(
                        af[mt], bfr[nt], acc[mt][nt], 0, 0, 0);
        }
        __syncthreads();   // LDS free for next half / the transpose
    }

    // ---- transpose accs -> O2b[p][k2] bf16 in LDS, A-fragment order ----
    // k2 = (nn&31)*32 + (mm&31); chunk c2=k2>>3; swizzle spreads writer lanes
    // over all 8 bank groups: pc = c2 ^ ((c2>>3)&7) ^ (p&7).
    unsigned short* O2b = (unsigned short*)smem;        // 16 x 1024 bf16 = 32 KB
    #pragma unroll
    for (int mt = 0; mt < 4; mt++) {
        int mmb = wr * 64 + mt * 16 + kg * 4;           // + r (r stays in-chunk)
        #pragma unroll
        for (int nt = 0; nt < 4; nt++) {
            int nn = wc * 64 + nt * 16 + r16;
            int p  = ((mmb >> 5) << 2) | (nn >> 5);     // pair = i_loc*4 + j_loc
            int k2 = ((nn & 31) << 5) | (mmb & 31);
            int c2 = k2 >> 3;
            int pc = c2 ^ ((c2 >> 3) & 7) ^ (p & 7);
            *(uint2*)(O2b + p * 1024 + pc * 8 + (k2 & 7)) =
                make_uint2(pack2(acc[mt][nt][0], acc[mt][nt][1]),
                           pack2(acc[mt][nt][2], acc[mt][nt][3]));
        }
    }
    __syncthreads();

    // ---- stage 2: Z[16 pairs, 128] = O2[16,1024] @ Wo[1024,128] ----
    f32x4 acc2[2];
    acc2[0] = (f32x4){0.f, 0.f, 0.f, 0.f};
    acc2[1] = (f32x4){0.f, 0.f, 0.f, 0.f};
    const int p2 = r16;                                  // A-operand row = pair
    const unsigned short* O2r = O2b + p2 * 1024;
    const int psw = r16 & 7;
    // W2 block for this wave: zg = w*2 (+nt2); each load = contiguous 1KB/wave
    const unsigned short* wz = W2 + (size_t)(w * 2) * 16384 + r16 * 32 + kg * 8;
    #pragma unroll 8
    for (int s = 0; s < 32; s++) {
        int c2 = s * 4 + kg;
        int pc = c2 ^ ((c2 >> 3) & 7) ^ psw;
        bf8_t av  = *(const bf8_t*)(O2r + pc * 8);
        bf8_t wfa = *(const bf8_t*)(wz + s * 512);
        bf8_t wfb = *(const bf8_t*)(wz + 16384 + s * 512);
        acc2[0] = __builtin_amdgcn_mfma_f32_16x16x32_bf16(av, wfa, acc2[0], 0, 0, 0);
        acc2[1] = __builtin_amdgcn_mfma_f32_16x16x32_bf16(av, wfb, acc2[1], 0, 0, 0);
    }

    // ---- epilogue: scale by 1/(pair_mask+eps), add bias, store ----
    const int i0 = ti * 4, j0 = tj * 4;
    #pragma unroll
    for (int r = 0; r < 4; r++) {
        int p = kg * 4 + r;
        int i = i0 + (p >> 2), j = j0 + (p & 3);
        float recip = pmr[i * 256 + j];
        #pragma unroll
        for (int nt2 = 0; nt2 < 2; nt2++) {
            int z = w * 32 + nt2 * 16 + r16;
            out[((size_t)(i * 256 + j)) * 128 + z] = acc2[nt2][r] * recip + bo[z];
        }
    }
}

// ---------------------------------------------------------------------------
extern "C" void kernel_launch(void* const* d_in, const int* in_sizes, int n_in,
                              void* d_out, int out_size, void* d_ws, size_t ws_size,
                              hipStream_t stream)
{
    const float* m    = (const float*)d_in[0];
    const float* mask = (const float*)d_in[1];
    const float* gam  = (const float*)d_in[2];
    const float* bet  = (const float*)d_in[3];
    const float* Wa   = (const float*)d_in[4];
    const float* ba   = (const float*)d_in[5];
    const float* Wb   = (const float*)d_in[6];
    const float* bb   = (const float*)d_in[7];
    const float* Wo   = (const float*)d_in[8];
    const float* bo   = (const float*)d_in[9];
    float* out = (float*)d_out;

    unsigned short* aT  = (unsigned short*)d_ws;           // 8192*128 bf16 = 2 MB
    unsigned short* bT  = aT + 8192 * 128;                 // 2 MB
    unsigned short* W2  = bT + 8192 * 128;                 // 128*1024 bf16 = 256 KB
    unsigned short* WTb = W2 + 128 * 1024;                 // 64*256 bf16 = 32 KB
    float* pmr = (float*)(WTb + 64 * 256);                 // 256*256 fp32 = 256 KB

    k_prep   <<<  64, 256, 0, stream>>>(Wa, Wb, WTb);
    k_ln_proj<<<2816, 256, 0, stream>>>(m, mask, gam, bet, WTb, ba, bb, Wo,
                                        aT, bT, W2, pmr);
    k_outer  <<<4096, 256, 0, stream>>>(aT, bT, W2, pmr, bo, out);
}

// Round 5
// 186.563 us; speedup vs baseline: 1.3562x; 1.2267x over previous
//
#include <hip/hip_runtime.h>
#include <hip/hip_bf16.h>

// ---------------------------------------------------------------------------
// OuterProductMean (AlphaFold) fused MFMA implementation for gfx950.
//   B=1, N=128 (MSA depth), L=256, C_M=256, C_H=32, C_Z=128
// Pipeline (3 launches):
//   k_prep    : [Wa|Wb] fp32 -> WT bf16 [64][256] (h-major, c contiguous)
//   k_ln_proj : main blocks: LayerNorm + a/b projection (MFMA) -> aT/bT bf16
//               [8192][128] (row = l*32+h, col = MSA index n -> K-contiguous).
//               tail: W2 = Wo in bf16 *fragment-sequential* layout
//               (zg,s,r16,kg,e) so stage-2 wave loads are contiguous 1KB;
//               pm_recip[i,j] = 1/(sum_n mask[n,i]*mask[n,j] + 1e-8).
//   k_outer   : 32KB LDS (5 blocks/CU): K-split (2x K=64) staging for the
//               128x128 outer GEMM, transpose to bf16 A-fragment layout in the
//               same LDS, then [16,1024]@Wo[1024,128] GEMM, scale+bias epilogue.
//               NOTE: no min-waves clamp in __launch_bounds__ — forcing 5
//               waves/EU made the allocator spill the 16 f32x4 accumulators
//               (VGPR 48, +267 MB scratch HBM traffic). Compiler's natural
//               ~88 VGPR already allows 5 waves/EU.
// ---------------------------------------------------------------------------

typedef __attribute__((ext_vector_type(8))) short bf8_t;   // 8 x bf16 (4 VGPRs)
typedef __attribute__((ext_vector_type(4))) float f32x4;   // MFMA accumulator

__device__ __forceinline__ unsigned short f2bf(float f) {
    unsigned int u = __float_as_uint(f);
    u += 0x7fffu + ((u >> 16) & 1u);        // RNE (finite values only)
    return (unsigned short)(u >> 16);
}
__device__ __forceinline__ unsigned int pack2(float a, float b) {
    return (unsigned int)f2bf(a) | ((unsigned int)f2bf(b) << 16);
}

// ---------------------------------------------------------------------------
// WT[h][c] = (h<32 ? Wa[c][h] : Wb[c][h-32]), bf16. 16384 elems, 64 blocks.
__global__ __launch_bounds__(256) void k_prep(const float* __restrict__ Wa,
                                              const float* __restrict__ Wb,
                                              unsigned short* __restrict__ WTb) {
    int u = blockIdx.x * 256 + threadIdx.x;          // u = h*256 + c
    int h = u >> 8, c = u & 255;
    float v = (h < 32) ? Wa[c * 32 + h] : Wb[c * 32 + (h - 32)];
    WTb[u] = f2bf(v);
}

// ---------------------------------------------------------------------------
// Blocks [0,2048): LayerNorm + projection. Blocks [2048,2560): W2 build.
// Blocks [2560,2816): pair-mask reciprocal.
__global__ __launch_bounds__(256) void k_ln_proj(
    const float* __restrict__ gm, const float* __restrict__ gmask,
    const float* __restrict__ gamma, const float* __restrict__ beta,
    const unsigned short* __restrict__ WTb,
    const float* __restrict__ ba, const float* __restrict__ bb,
    const float* __restrict__ Wo,
    unsigned short* __restrict__ aT, unsigned short* __restrict__ bT,
    unsigned short* __restrict__ W2, float* __restrict__ pmr)
{
    const int tid = threadIdx.x;
    const int tail = (int)blockIdx.x - 2048;
    if (tail >= 0) {
        if (tail < 512) {
            // W2 fragment-sequential: (zg=z>>4, s=k'>>5, r16=z&15, kg=(k'>>3)&3, e=k'&7)
            // with k' = d*32+c, Wo element index u = (c*32+d)*128 + z.
            int u = tail * 256 + tid;                // u = k*128 + z (coalesced read)
            int k = u >> 7, z = u & 127;
            int c = k >> 5, d = k & 31;
            int kp = d * 32 + c;
            int dst = (((z >> 4) * 32 + (kp >> 5)) * 16 + (z & 15)) * 32
                      + ((kp >> 3) & 3) * 8 + (kp & 7);
            W2[dst] = f2bf(Wo[u]);
        } else {
            int u = (tail - 512) * 256 + tid;        // u = i*256 + j
            int i = u >> 8, j = u & 255;
            float s = 0.f;
            #pragma unroll 8
            for (int n = 0; n < 128; n++)
                s += gmask[n * 256 + i] * gmask[n * 256 + j];
            pmr[u] = 1.f / (s + 1e-8f);
        }
        return;
    }

    __shared__ __align__(16) unsigned short xlb[16 * 256]; // [row][c] bf16, swizzled
    __shared__ float vl[16 * 64];                          // [n-row][h]
    const int lane = tid & 63, w = tid >> 6;
    const int l = blockIdx.x & 255, n0 = ((int)blockIdx.x >> 8) << 4;

    const float4 g4  = ((const float4*)gamma)[lane];
    const float4 be4 = ((const float4*)beta)[lane];

    // ---- phase 1: LN (wave per row, 4 rows per wave) ----
    #pragma unroll
    for (int j = 0; j < 4; j++) {
        int row = w * 4 + j;
        int n = n0 + row;
        float4 v = ((const float4*)(gm + ((size_t)n * 256 + l) * 256))[lane];
        float s = v.x + v.y + v.z + v.w;
        float q = v.x * v.x + v.y * v.y + v.z * v.z + v.w * v.w;
        #pragma unroll
        for (int off = 1; off < 64; off <<= 1) {
            s += __shfl_xor(s, off);
            q += __shfl_xor(q, off);
        }
        float mean = s * (1.f / 256.f);
        float var = fmaxf(q * (1.f / 256.f) - mean * mean, 0.f);
        float rstd = rsqrtf(var + 1e-5f);
        float x0 = (v.x - mean) * rstd * g4.x + be4.x;
        float x1 = (v.y - mean) * rstd * g4.y + be4.y;
        float x2 = (v.z - mean) * rstd * g4.z + be4.z;
        float x3 = (v.w - mean) * rstd * g4.w + be4.w;
        int c8s = lane ^ ((row & 7) << 1);               // 8B-chunk XOR swizzle
        *(uint2*)((char*)xlb + row * 512 + (c8s << 3)) =
            make_uint2(pack2(x0, x1), pack2(x2, x3));
    }
    __syncthreads();

    // ---- phase 2: projection via MFMA (wave w -> h-cols w*16..w*16+15) ----
    const int kg = lane >> 4, r16 = lane & 15;
    const int h = w * 16 + r16;
    f32x4 acc = {0.f, 0.f, 0.f, 0.f};
    #pragma unroll
    for (int ks = 0; ks < 8; ks++) {
        int c8 = ks * 8 + kg * 2;                        // even -> 16B pair intact
        bf8_t af = *(const bf8_t*)((char*)xlb + r16 * 512 +
                                   ((c8 ^ ((r16 & 7) << 1)) << 3));
        bf8_t wf = *(const bf8_t*)(WTb + (size_t)h * 256 + ks * 32 + kg * 8);
        acc = __builtin_amdgcn_mfma_f32_16x16x32_bf16(af, wf, acc, 0, 0, 0);
    }
    float bias = (h < 32) ? ba[h] : bb[h - 32];
    #pragma unroll
    for (int r = 0; r < 4; r++) {
        int nrow = kg * 4 + r;                           // C/D row = MSA row index
        float mk = gmask[(size_t)(n0 + nrow) * 256 + l];
        vl[nrow * 64 + h] = (acc[r] + bias) * mk;
    }
    __syncthreads();

    // ---- phase 3: repack, 8 n-values per thread, 16B stores ----
    if (tid < 128) {
        int row = tid >> 1, half = tid & 1;              // row = h index 0..63
        int hh = row & 31;
        unsigned short* dst = (row < 32) ? aT : bT;
        unsigned int pk[4];
        #pragma unroll
        for (int jj = 0; jj < 4; jj++)
            pk[jj] = pack2(vl[(half * 8 + 2 * jj) * 64 + row],
                           vl[(half * 8 + 2 * jj + 1) * 64 + row]);
        *(uint4*)(dst + ((size_t)l * 32 + hh) * 128 + n0 + half * 8) =
            make_uint4(pk[0], pk[1], pk[2], pk[3]);
    }
}

// ---------------------------------------------------------------------------
// Fused outer-product + Wo projection. 32KB LDS -> 5 blocks/CU (LDS-limited).
// Grid 4096 = 64 tj (fast) x 64 ti. Block 256 thr = 4 waves (2x2 quadrants).
__global__ __launch_bounds__(256) void k_outer(
    const unsigned short* __restrict__ aT, const unsigned short* __restrict__ bT,
    const unsigned short* __restrict__ W2, const float* __restrict__ pmr,
    const float* __restrict__ bo, float* __restrict__ out)
{
    __shared__ __align__(16) char smem[32768];
    const int tid = threadIdx.x, lane = tid & 63, w = tid >> 6;
    const int wr = w >> 1, wc = w & 1;
    const int tj = blockIdx.x & 63, ti = blockIdx.x >> 6;
    const int kg = lane >> 4, r16 = lane & 15;

    f32x4 acc[4][4];
    #pragma unroll
    for (int mt = 0; mt < 4; mt++)
        #pragma unroll
        for (int nt = 0; nt < 4; nt++)
            acc[mt][nt] = (f32x4){0.f, 0.f, 0.f, 0.f};

    const uint4* gA = (const uint4*)(aT + (size_t)ti * 16384);
    const uint4* gB = (const uint4*)(bT + (size_t)tj * 16384);

    // ---- stage 1: 128x128 outer tile in two K=64 rounds (16KB A + 16KB B) ----
    #pragma unroll
    for (int half = 0; half < 2; half++) {
        #pragma unroll
        for (int k = 0; k < 4; k++) {
            int g = k * 256 + tid;                       // 0..1023
            int row = g >> 3, ch = g & 7;                // row 0..127, chunk-in-half
            int dsto = row * 128 + ((ch ^ (row & 7)) << 4);
            *(uint4*)(smem + dsto)         = gA[row * 16 + half * 8 + ch];
            *(uint4*)(smem + 16384 + dsto) = gB[row * 16 + half * 8 + ch];
        }
        __syncthreads();
        #pragma unroll
        for (int ks2 = 0; ks2 < 2; ks2++) {
            bf8_t af[4], bfr[4];
            int ch = ks2 * 4 + kg;                       // chunk within half
            #pragma unroll
            for (int mt = 0; mt < 4; mt++) {
                int mm = wr * 64 + mt * 16 + r16;
                af[mt] = *(const bf8_t*)(smem + mm * 128 + ((ch ^ (mm & 7)) << 4));
                int nn = wc * 64 + mt * 16 + r16;
                bfr[mt] = *(const bf8_t*)(smem + 16384 + nn * 128 + ((ch ^ (nn & 7)) << 4));
            }
            #pragma unroll
            for (int mt = 0; mt < 4; mt++)
                #pragma unroll
                for (int nt = 0; nt < 4; nt++)
                    acc[mt][nt] = __builtin_amdgcn_mfma_f32_16x16x32_bf16(
                        af[mt], bfr[nt], acc[mt][nt], 0, 0, 0);
        }
        __syncthreads();   // LDS free for next half / the transpose
    }

    // ---- transpose accs -> O2b[p][k2] bf16 in LDS, A-fragment order ----
    // k2 = (nn&31)*32 + (mm&31); chunk c2=k2>>3; swizzle spreads writer lanes
    // over all 8 bank groups: pc = c2 ^ ((c2>>3)&7) ^ (p&7).
    unsigned short* O2b = (unsigned short*)smem;        // 16 x 1024 bf16 = 32 KB
    #pragma unroll
    for (int mt = 0; mt < 4; mt++) {
        int mmb = wr * 64 + mt * 16 + kg * 4;           // + r (r stays in-chunk)
        #pragma unroll
        for (int nt = 0; nt < 4; nt++) {
            int nn = wc * 64 + nt * 16 + r16;
            int p  = ((mmb >> 5) << 2) | (nn >> 5);     // pair = i_loc*4 + j_loc
            int k2 = ((nn & 31) << 5) | (mmb & 31);
            int c2 = k2 >> 3;
            int pc = c2 ^ ((c2 >> 3) & 7) ^ (p & 7);
            *(uint2*)(O2b + p * 1024 + pc * 8 + (k2 & 7)) =
                make_uint2(pack2(acc[mt][nt][0], acc[mt][nt][1]),
                           pack2(acc[mt][nt][2], acc[mt][nt][3]));
        }
    }
    __syncthreads();

    // ---- stage 2: Z[16 pairs, 128] = O2[16,1024] @ Wo[1024,128] ----
    f32x4 acc2[2];
    acc2[0] = (f32x4){0.f, 0.f, 0.f, 0.f};
    acc2[1] = (f32x4){0.f, 0.f, 0.f, 0.f};
    const int p2 = r16;                                  // A-operand row = pair
    const unsigned short* O2r = O2b + p2 * 1024;
    const int psw = r16 & 7;
    // W2 block for this wave: zg = w*2 (+nt2); each load = contiguous 1KB/wave
    const unsigned short* wz = W2 + (size_t)(w * 2) * 16384 + r16 * 32 + kg * 8;
    #pragma unroll 8
    for (int s = 0; s < 32; s++) {
        int c2 = s * 4 + kg;
        int pc = c2 ^ ((c2 >> 3) & 7) ^ psw;
        bf8_t av  = *(const bf8_t*)(O2r + pc * 8);
        bf8_t wfa = *(const bf8_t*)(wz + s * 512);
        bf8_t wfb = *(const bf8_t*)(wz + 16384 + s * 512);
        acc2[0] = __builtin_amdgcn_mfma_f32_16x16x32_bf16(av, wfa, acc2[0], 0, 0, 0);
        acc2[1] = __builtin_amdgcn_mfma_f32_16x16x32_bf16(av, wfb, acc2[1], 0, 0, 0);
    }

    // ---- epilogue: scale by 1/(pair_mask+eps), add bias, store ----
    const int i0 = ti * 4, j0 = tj * 4;
    #pragma unroll
    for (int r = 0; r < 4; r++) {
        int p = kg * 4 + r;
        int i = i0 + (p >> 2), j = j0 + (p & 3);
        float recip = pmr[i * 256 + j];
        #pragma unroll
        for (int nt2 = 0; nt2 < 2; nt2++) {
            int z = w * 32 + nt2 * 16 + r16;
            out[((size_t)(i * 256 + j)) * 128 + z] = acc2[nt2][r] * recip + bo[z];
        }
    }
}

// ---------------------------------------------------------------------------
extern "C" void kernel_launch(void* const* d_in, const int* in_sizes, int n_in,
                              void* d_out, int out_size, void* d_ws, size_t ws_size,
                              hipStream_t stream)
{
    const float* m    = (const float*)d_in[0];
    const float* mask = (const float*)d_in[1];
    const float* gam  = (const float*)d_in[2];
    const float* bet  = (const float*)d_in[3];
    const float* Wa   = (const float*)d_in[4];
    const float* ba   = (const float*)d_in[5];
    const float* Wb   = (const float*)d_in[6];
    const float* bb   = (const float*)d_in[7];
    const float* Wo   = (const float*)d_in[8];
    const float* bo   = (const float*)d_in[9];
    float* out = (float*)d_out;

    unsigned short* aT  = (unsigned short*)d_ws;           // 8192*128 bf16 = 2 MB
    unsigned short* bT  = aT + 8192 * 128;                 // 2 MB
    unsigned short* W2  = bT + 8192 * 128;                 // 128*1024 bf16 = 256 KB
    unsigned short* WTb = W2 + 128 * 1024;                 // 64*256 bf16 = 32 KB
    float* pmr = (float*)(WTb + 64 * 256);                 // 256*256 fp32 = 256 KB

    k_prep   <<<  64, 256, 0, stream>>>(Wa, Wb, WTb);
    k_ln_proj<<<2816, 256, 0, stream>>>(m, mask, gam, bet, WTb, ba, bb, Wo,
                                        aT, bT, W2, pmr);
    k_outer  <<<4096, 256, 0, stream>>>(aT, bT, W2, pmr, bo, out);
}

// Round 6
// 185.073 us; speedup vs baseline: 1.3671x; 1.0080x over previous
//
#include <hip/hip_runtime.h>
#include <hip/hip_bf16.h>

// ---------------------------------------------------------------------------
// OuterProductMean (AlphaFold) fused MFMA implementation for gfx950.
//   B=1, N=128 (MSA depth), L=256, C_M=256, C_H=32, C_Z=128
// Pipeline (3 launches):
//   k_prep    : [Wa|Wb] fp32 -> WT bf16 [64][256] (h-major, c contiguous)
//   k_ln_proj : main blocks: LayerNorm + a/b projection (MFMA) -> aT/bT bf16
//               [8192][128] (row = l*32+h, col = MSA index n -> K-contiguous).
//               tail: W2 = Wo bf16 fragment-sequential (zg,s,r16,kg,e);
//               pm_recip[i,j] = 1/(sum_n mask[n,i]*mask[n,j] + 1e-8).
//   k_outer   : 512 thr / 8 waves, 32KB LDS. Each wave owns a 64x32 quadrant
//               of the 128x128 outer tile -> 32 AGPR acc/wave (vs 64 with 4
//               waves) so waves/SIMD rises to ~5 (reg-file is unified
//               VGPR+AGPR on gfx950; R5's 4-wave version cost ~140 regs/wave
//               -> 3 waves/SIMD -> 28% occupancy). Stage-2 splits z 8 ways
//               (16 z/wave), W2 read exactly once per block.
// ---------------------------------------------------------------------------

typedef __attribute__((ext_vector_type(8))) short bf8_t;   // 8 x bf16 (4 VGPRs)
typedef __attribute__((ext_vector_type(4))) float f32x4;   // MFMA accumulator

__device__ __forceinline__ unsigned short f2bf(float f) {
    unsigned int u = __float_as_uint(f);
    u += 0x7fffu + ((u >> 16) & 1u);        // RNE (finite values only)
    return (unsigned short)(u >> 16);
}
__device__ __forceinline__ unsigned int pack2(float a, float b) {
    return (unsigned int)f2bf(a) | ((unsigned int)f2bf(b) << 16);
}

// ---------------------------------------------------------------------------
// WT[h][c] = (h<32 ? Wa[c][h] : Wb[c][h-32]), bf16. 16384 elems, 64 blocks.
__global__ __launch_bounds__(256) void k_prep(const float* __restrict__ Wa,
                                              const float* __restrict__ Wb,
                                              unsigned short* __restrict__ WTb) {
    int u = blockIdx.x * 256 + threadIdx.x;          // u = h*256 + c
    int h = u >> 8, c = u & 255;
    float v = (h < 32) ? Wa[c * 32 + h] : Wb[c * 32 + (h - 32)];
    WTb[u] = f2bf(v);
}

// ---------------------------------------------------------------------------
// Blocks [0,2048): LayerNorm + projection. Blocks [2048,2560): W2 build.
// Blocks [2560,2816): pair-mask reciprocal.
__global__ __launch_bounds__(256) void k_ln_proj(
    const float* __restrict__ gm, const float* __restrict__ gmask,
    const float* __restrict__ gamma, const float* __restrict__ beta,
    const unsigned short* __restrict__ WTb,
    const float* __restrict__ ba, const float* __restrict__ bb,
    const float* __restrict__ Wo,
    unsigned short* __restrict__ aT, unsigned short* __restrict__ bT,
    unsigned short* __restrict__ W2, float* __restrict__ pmr)
{
    const int tid = threadIdx.x;
    const int tail = (int)blockIdx.x - 2048;
    if (tail >= 0) {
        if (tail < 512) {
            // W2 fragment-sequential: (zg=z>>4, s=k'>>5, r16=z&15, kg=(k'>>3)&3, e=k'&7)
            // with k' = d*32+c, Wo element index u = (c*32+d)*128 + z.
            int u = tail * 256 + tid;                // u = k*128 + z (coalesced read)
            int k = u >> 7, z = u & 127;
            int c = k >> 5, d = k & 31;
            int kp = d * 32 + c;
            int dst = (((z >> 4) * 32 + (kp >> 5)) * 16 + (z & 15)) * 32
                      + ((kp >> 3) & 3) * 8 + (kp & 7);
            W2[dst] = f2bf(Wo[u]);
        } else {
            int u = (tail - 512) * 256 + tid;        // u = i*256 + j
            int i = u >> 8, j = u & 255;
            float s = 0.f;
            #pragma unroll 8
            for (int n = 0; n < 128; n++)
                s += gmask[n * 256 + i] * gmask[n * 256 + j];
            pmr[u] = 1.f / (s + 1e-8f);
        }
        return;
    }

    __shared__ __align__(16) unsigned short xlb[16 * 256]; // [row][c] bf16, swizzled
    __shared__ float vl[16 * 64];                          // [n-row][h]
    const int lane = tid & 63, w = tid >> 6;
    const int l = blockIdx.x & 255, n0 = ((int)blockIdx.x >> 8) << 4;

    const float4 g4  = ((const float4*)gamma)[lane];
    const float4 be4 = ((const float4*)beta)[lane];

    // ---- phase 1: LN (wave per row, 4 rows per wave) ----
    #pragma unroll
    for (int j = 0; j < 4; j++) {
        int row = w * 4 + j;
        int n = n0 + row;
        float4 v = ((const float4*)(gm + ((size_t)n * 256 + l) * 256))[lane];
        float s = v.x + v.y + v.z + v.w;
        float q = v.x * v.x + v.y * v.y + v.z * v.z + v.w * v.w;
        #pragma unroll
        for (int off = 1; off < 64; off <<= 1) {
            s += __shfl_xor(s, off);
            q += __shfl_xor(q, off);
        }
        float mean = s * (1.f / 256.f);
        float var = fmaxf(q * (1.f / 256.f) - mean * mean, 0.f);
        float rstd = rsqrtf(var + 1e-5f);
        float x0 = (v.x - mean) * rstd * g4.x + be4.x;
        float x1 = (v.y - mean) * rstd * g4.y + be4.y;
        float x2 = (v.z - mean) * rstd * g4.z + be4.z;
        float x3 = (v.w - mean) * rstd * g4.w + be4.w;
        int c8s = lane ^ ((row & 7) << 1);               // 8B-chunk XOR swizzle
        *(uint2*)((char*)xlb + row * 512 + (c8s << 3)) =
            make_uint2(pack2(x0, x1), pack2(x2, x3));
    }
    __syncthreads();

    // ---- phase 2: projection via MFMA (wave w -> h-cols w*16..w*16+15) ----
    const int kg = lane >> 4, r16 = lane & 15;
    const int h = w * 16 + r16;
    f32x4 acc = {0.f, 0.f, 0.f, 0.f};
    #pragma unroll
    for (int ks = 0; ks < 8; ks++) {
        int c8 = ks * 8 + kg * 2;                        // even -> 16B pair intact
        bf8_t af = *(const bf8_t*)((char*)xlb + r16 * 512 +
                                   ((c8 ^ ((r16 & 7) << 1)) << 3));
        bf8_t wf = *(const bf8_t*)(WTb + (size_t)h * 256 + ks * 32 + kg * 8);
        acc = __builtin_amdgcn_mfma_f32_16x16x32_bf16(af, wf, acc, 0, 0, 0);
    }
    float bias = (h < 32) ? ba[h] : bb[h - 32];
    #pragma unroll
    for (int r = 0; r < 4; r++) {
        int nrow = kg * 4 + r;                           // C/D row = MSA row index
        float mk = gmask[(size_t)(n0 + nrow) * 256 + l];
        vl[nrow * 64 + h] = (acc[r] + bias) * mk;
    }
    __syncthreads();

    // ---- phase 3: repack, 8 n-values per thread, 16B stores ----
    if (tid < 128) {
        int row = tid >> 1, half = tid & 1;              // row = h index 0..63
        int hh = row & 31;
        unsigned short* dst = (row < 32) ? aT : bT;
        unsigned int pk[4];
        #pragma unroll
        for (int jj = 0; jj < 4; jj++)
            pk[jj] = pack2(vl[(half * 8 + 2 * jj) * 64 + row],
                           vl[(half * 8 + 2 * jj + 1) * 64 + row]);
        *(uint4*)(dst + ((size_t)l * 32 + hh) * 128 + n0 + half * 8) =
            make_uint4(pk[0], pk[1], pk[2], pk[3]);
    }
}

// ---------------------------------------------------------------------------
// Fused outer-product + Wo projection. 512 thr = 8 waves; 32KB LDS.
// Grid 4096 = 64 tj (fast) x 64 ti. Wave quadrant: wr(2) x wc(4) -> 64x32.
__global__ __launch_bounds__(512) void k_outer(
    const unsigned short* __restrict__ aT, const unsigned short* __restrict__ bT,
    const unsigned short* __restrict__ W2, const float* __restrict__ pmr,
    const float* __restrict__ bo, float* __restrict__ out)
{
    __shared__ __align__(16) char smem[32768];
    const int tid = threadIdx.x, lane = tid & 63, w = tid >> 6;   // 8 waves
    const int wr = w >> 2, wc = w & 3;
    const int tj = blockIdx.x & 63, ti = blockIdx.x >> 6;
    const int kg = lane >> 4, r16 = lane & 15;

    f32x4 acc[4][2];
    #pragma unroll
    for (int mt = 0; mt < 4; mt++)
        #pragma unroll
        for (int nt = 0; nt < 2; nt++)
            acc[mt][nt] = (f32x4){0.f, 0.f, 0.f, 0.f};

    const uint4* gA = (const uint4*)(aT + (size_t)ti * 16384);
    const uint4* gB = (const uint4*)(bT + (size_t)tj * 16384);

    // ---- stage 1: 128x128 outer tile in two K=64 rounds (16KB A + 16KB B) ----
    #pragma unroll
    for (int half = 0; half < 2; half++) {
        #pragma unroll
        for (int k = 0; k < 2; k++) {
            int g = k * 512 + tid;                       // 0..1023
            int row = g >> 3, ch = g & 7;                // row 0..127, chunk-in-half
            int dsto = row * 128 + ((ch ^ (row & 7)) << 4);
            *(uint4*)(smem + dsto)         = gA[row * 16 + half * 8 + ch];
            *(uint4*)(smem + 16384 + dsto) = gB[row * 16 + half * 8 + ch];
        }
        __syncthreads();
        #pragma unroll
        for (int ks2 = 0; ks2 < 2; ks2++) {
            bf8_t af[4], bfr[2];
            int ch = ks2 * 4 + kg;                       // chunk within half
            #pragma unroll
            for (int mt = 0; mt < 4; mt++) {
                int mm = wr * 64 + mt * 16 + r16;
                af[mt] = *(const bf8_t*)(smem + mm * 128 + ((ch ^ (mm & 7)) << 4));
            }
            #pragma unroll
            for (int nt = 0; nt < 2; nt++) {
                int nn = wc * 32 + nt * 16 + r16;
                bfr[nt] = *(const bf8_t*)(smem + 16384 + nn * 128 + ((ch ^ (nn & 7)) << 4));
            }
            #pragma unroll
            for (int mt = 0; mt < 4; mt++)
                #pragma unroll
                for (int nt = 0; nt < 2; nt++)
                    acc[mt][nt] = __builtin_amdgcn_mfma_f32_16x16x32_bf16(
                        af[mt], bfr[nt], acc[mt][nt], 0, 0, 0);
        }
        __syncthreads();   // LDS free for next half / the transpose
    }

    // ---- transpose accs -> O2b[p][k2] bf16 in LDS, A-fragment order ----
    // k2 = (nn&31)*32 + (mm&31); chunk c2=k2>>3; swizzle spreads writer lanes
    // over all 8 bank groups: pc = c2 ^ ((c2>>3)&7) ^ (p&7).
    unsigned short* O2b = (unsigned short*)smem;        // 16 x 1024 bf16 = 32 KB
    #pragma unroll
    for (int mt = 0; mt < 4; mt++) {
        int mmb = wr * 64 + mt * 16 + kg * 4;           // + r (r stays in-chunk)
        #pragma unroll
        for (int nt = 0; nt < 2; nt++) {
            int nn = wc * 32 + nt * 16 + r16;
            int p  = ((mmb >> 5) << 2) | (nn >> 5);     // pair = i_loc*4 + j_loc
            int k2 = ((nn & 31) << 5) | (mmb & 31);
            int c2 = k2 >> 3;
            int pc = c2 ^ ((c2 >> 3) & 7) ^ (p & 7);
            *(uint2*)(O2b + p * 1024 + pc * 8 + (k2 & 7)) =
                make_uint2(pack2(acc[mt][nt][0], acc[mt][nt][1]),
                           pack2(acc[mt][nt][2], acc[mt][nt][3]));
        }
    }
    __syncthreads();

    // ---- stage 2: Z[16 pairs, 128] = O2[16,1024] @ Wo[1024,128] ----
    // Wave w handles z in [w*16, w*16+16): reads its 32KB slice of W2 once.
    f32x4 acc2 = {0.f, 0.f, 0.f, 0.f};
    const unsigned short* O2r = O2b + r16 * 1024;        // A-operand row = pair
    const int psw = r16 & 7;
    const unsigned short* wz = W2 + (size_t)w * 16384 + r16 * 32 + kg * 8;
    #pragma unroll 8
    for (int s = 0; s < 32; s++) {
        int c2 = s * 4 + kg;
        int pc = c2 ^ ((c2 >> 3) & 7) ^ psw;
        bf8_t av = *(const bf8_t*)(O2r + pc * 8);
        bf8_t wf = *(const bf8_t*)(wz + s * 512);
        acc2 = __builtin_amdgcn_mfma_f32_16x16x32_bf16(av, wf, acc2, 0, 0, 0);
    }

    // ---- epilogue: scale by 1/(pair_mask+eps), add bias, store ----
    const int i0 = ti * 4, j0 = tj * 4;
    const int z = w * 16 + r16;
    const float boz = bo[z];
    #pragma unroll
    for (int r = 0; r < 4; r++) {
        int p = kg * 4 + r;
        int i = i0 + (p >> 2), j = j0 + (p & 3);
        float recip = pmr[i * 256 + j];
        out[((size_t)(i * 256 + j)) * 128 + z] = acc2[r] * recip + boz;
    }
}

// ---------------------------------------------------------------------------
extern "C" void kernel_launch(void* const* d_in, const int* in_sizes, int n_in,
                              void* d_out, int out_size, void* d_ws, size_t ws_size,
                              hipStream_t stream)
{
    const float* m    = (const float*)d_in[0];
    const float* mask = (const float*)d_in[1];
    const float* gam  = (const float*)d_in[2];
    const float* bet  = (const float*)d_in[3];
    const float* Wa   = (const float*)d_in[4];
    const float* ba   = (const float*)d_in[5];
    const float* Wb   = (const float*)d_in[6];
    const float* bb   = (const float*)d_in[7];
    const float* Wo   = (const float*)d_in[8];
    const float* bo   = (const float*)d_in[9];
    float* out = (float*)d_out;

    unsigned short* aT  = (unsigned short*)d_ws;           // 8192*128 bf16 = 2 MB
    unsigned short* bT  = aT + 8192 * 128;                 // 2 MB
    unsigned short* W2  = bT + 8192 * 128;                 // 128*1024 bf16 = 256 KB
    unsigned short* WTb = W2 + 128 * 1024;                 // 64*256 bf16 = 32 KB
    float* pmr = (float*)(WTb + 64 * 256);                 // 256*256 fp32 = 256 KB

    k_prep   <<<  64, 256, 0, stream>>>(Wa, Wb, WTb);
    k_ln_proj<<<2816, 256, 0, stream>>>(m, mask, gam, bet, WTb, ba, bb, Wo,
                                        aT, bT, W2, pmr);
    k_outer  <<<4096, 512, 0, stream>>>(aT, bT, W2, pmr, bo, out);
}